// Round 1
// 1082.776 us; speedup vs baseline: 1.1139x; 1.1139x over previous
//
#include <hip/hip_runtime.h>
#include <stdint.h>
#include <math.h>

typedef __attribute__((ext_vector_type(8))) short short8;
typedef __attribute__((ext_vector_type(4))) float f32x4;

typedef const __attribute__((address_space(1))) void* gas_ptr;
typedef __attribute__((address_space(3))) void* las_ptr;

__device__ __forceinline__ void gld_lds16(const void* g, void* l) {
    // async global->LDS, 16B per lane, LDS dest = wave-uniform base + lane*16
    __builtin_amdgcn_global_load_lds((gas_ptr)g, (las_ptr)l, 16, 0, 0);
}

__device__ __forceinline__ unsigned short f32_to_bf16_rne(float f) {
    unsigned u = __builtin_bit_cast(unsigned, f);
    u += 0x7FFFu + ((u >> 16) & 1u);
    return (unsigned short)(u >> 16);
}

// ---------------- stats: pass 1 (per-block partial sum/sumsq in double) ----------------
__global__ void stats_partial_kernel(const float* __restrict__ w, int n4, double* __restrict__ partials) {
    __shared__ double ssum[256];
    __shared__ double ssq[256];
    int t = threadIdx.x;
    long i = (long)blockIdx.x * blockDim.x + t;
    long stride = (long)gridDim.x * blockDim.x;
    double s = 0.0, q = 0.0;
    for (; i < n4; i += stride) {
        float4 v = ((const float4*)w)[i];
        s += (double)v.x + (double)v.y + (double)v.z + (double)v.w;
        q += (double)v.x * v.x + (double)v.y * v.y + (double)v.z * v.z + (double)v.w * v.w;
    }
    ssum[t] = s; ssq[t] = q;
    __syncthreads();
    for (int off = 128; off > 0; off >>= 1) {
        if (t < off) { ssum[t] += ssum[t + off]; ssq[t] += ssq[t + off]; }
        __syncthreads();
    }
    if (t == 0) {
        partials[2 * blockIdx.x]     = ssum[0];
        partials[2 * blockIdx.x + 1] = ssq[0];
    }
}

// ---------------- stats: pass 2 (finalize -> lower/upper bounds as float) ----------------
__global__ void stats_final_kernel(const double* __restrict__ partials, int nblocks, long n,
                                   float* __restrict__ bounds) {
    __shared__ double ssum[256];
    __shared__ double ssq[256];
    int t = threadIdx.x;
    double s = 0.0, q = 0.0;
    for (int i = t; i < nblocks; i += 256) {
        s += partials[2 * i];
        q += partials[2 * i + 1];
    }
    ssum[t] = s; ssq[t] = q;
    __syncthreads();
    for (int off = 128; off > 0; off >>= 1) {
        if (t < off) { ssum[t] += ssum[t + off]; ssq[t] += ssq[t + off]; }
        __syncthreads();
    }
    if (t == 0) {
        double sum = ssum[0], sumsq = ssq[0];
        double mean = sum / (double)n;
        double var = (sumsq - sum * sum / (double)n) / (double)(n - 1); // ddof=1
        double sd = sqrt(var);
        bounds[0] = (float)(mean - sd);
        bounds[1] = (float)(mean + sd);
    }
}

// ---------------- binarize weight -> bf16 bits (grid-stride, 8 elems/thread/iter) ----------------
__global__ void binarize_w_kernel(const float* __restrict__ w, const float* __restrict__ bounds,
                                  unsigned short* __restrict__ wb, long n8) {
    float lo = bounds[0], hi = bounds[1];
    long i = (long)blockIdx.x * blockDim.x + threadIdx.x;
    long stride = (long)gridDim.x * blockDim.x;
    for (; i < n8; i += stride) {
        float4 v0 = ((const float4*)w)[2 * i];
        float4 v1 = ((const float4*)w)[2 * i + 1];
        float r[8] = {v0.x, v0.y, v0.z, v0.w, v1.x, v1.y, v1.z, v1.w};
        short8 o;
#pragma unroll
        for (int j = 0; j < 8; j++) {
            float f = r[j];
            bool outlier = (f < lo) || (f > hi);
            float b = outlier ? f : (f > 0.f ? 1.f : (f < 0.f ? -1.f : 0.f));
            o[j] = (short)f32_to_bf16_rne(b);
        }
        ((short8*)wb)[i] = o;
    }
}

// ---------------- convert x -> bf16 bits (grid-stride, 8 elems/thread/iter) ----------------
__global__ void convert_x_kernel(const float* __restrict__ x, unsigned short* __restrict__ xb, long n8) {
    long i = (long)blockIdx.x * blockDim.x + threadIdx.x;
    long stride = (long)gridDim.x * blockDim.x;
    for (; i < n8; i += stride) {
        float4 v0 = ((const float4*)x)[2 * i];
        float4 v1 = ((const float4*)x)[2 * i + 1];
        short8 o;
        o[0] = (short)f32_to_bf16_rne(v0.x);
        o[1] = (short)f32_to_bf16_rne(v0.y);
        o[2] = (short)f32_to_bf16_rne(v0.z);
        o[3] = (short)f32_to_bf16_rne(v0.w);
        o[4] = (short)f32_to_bf16_rne(v1.x);
        o[5] = (short)f32_to_bf16_rne(v1.y);
        o[6] = (short)f32_to_bf16_rne(v1.z);
        o[7] = (short)f32_to_bf16_rne(v1.w);
        ((short8*)xb)[i] = o;
    }
}

// ---------------- bf16 MFMA GEMM, 256x256 8-phase counted-vmcnt template ----------------
// C[M,N] = A[M,K] * B[N,K]^T + bias. 512 threads = 8 waves (2M x 4N), each wave 128x64.
// BK=64; LDS = 2 x (A 32KB + B 32KB) = 128KB double buffer.
// Per K-tile: 4 phases; phase q: {stage 1 half-tile of a future tile, ds_read quadrant q
// (phase 0 also reads all B-frags into regs), barrier, lgkmcnt(0), setprio(1), 16 MFMA,
// setprio(0), [q==3: vmcnt(6)], barrier}. vmcnt never drains to 0 in steady state.
// Staging schedule (half-tiles: B0,B1 = B rows 0-127/128-255; A0,A1 likewise):
//   phase 0: (u+1).A1   phase 1: (u+2).B0   phase 2: (u+2).B1   phase 3: (u+2).A0
// Read-complete-before-restage: B fully read (into regs) in phase 0; A rows 0-63 phase 0,
// 64-127 phase 1, 128-191 phase 2, 192-255 phase 3 -> every stage targets a region whose
// last reader finished >=1 barrier earlier.
#define BM 256
#define BN 256
#define BK 64

__global__ __launch_bounds__(512, 2) void gemm_8phase_kernel(
    const unsigned short* __restrict__ A,   // [M,K] bf16 bits
    const unsigned short* __restrict__ B,   // [N,K] bf16 bits
    const float* __restrict__ bias,         // [N]
    float* __restrict__ C,                  // [M,N] fp32
    int M, int N, int K)
{
    __shared__ __align__(16) unsigned short As[2][BM * BK]; // 2 x 32KB
    __shared__ __align__(16) unsigned short Bs[2][BN * BK]; // 2 x 32KB

    const int t = threadIdx.x;
    const int wave = t >> 6;
    const int lane = t & 63;
    const int wm = wave >> 2;      // 0..1 -> 128-row half (interleaved by quadrant)
    const int wn = wave & 3;       // 0..3 -> 64-col block
    const int lm = lane & 15;
    const int quad = lane >> 4;

    // XCD-aware bijective swizzle (gridDim.x % 8 == 0 here: 64*16 = 1024)
    const int nwg = gridDim.x;
    int id = blockIdx.x;
    if ((nwg & 7) == 0) id = (id & 7) * (nwg >> 3) + (id >> 3);
    const int nbn = N / BN;
    const int tile_m = (id / nbn) * BM;
    const int tile_n = (id % nbn) * BN;

    // staging geometry: one issue = 512 threads x 16B = 64 rows x 64 cols.
    // thread t covers chunk t: row = t>>3, lds slot = t&7, global chunk = slot ^ (row&7)
    // (pre-swizzled global source; LDS dest stays linear for global_load_lds)
    const int srow = t >> 3;
    const int scol = ((t & 7) ^ (srow & 7)) * 8;
    const int lds_wbase = wave * 512;

    const unsigned short* Abase = A + (size_t)tile_m * K;
    const unsigned short* Bbase = B + (size_t)tile_n * K;

    auto stageA = [&](int u2, int h) {
        const unsigned short* g = Abase + (size_t)(h * 128 + srow) * K + u2 * BK + scol;
        unsigned short* l = &As[u2 & 1][h * 8192 + lds_wbase];
        gld_lds16(g, l);
        gld_lds16(g + (size_t)64 * K, l + 4096);
    };
    auto stageB = [&](int u2, int h) {
        const unsigned short* g = Bbase + (size_t)(h * 128 + srow) * K + u2 * BK + scol;
        unsigned short* l = &Bs[u2 & 1][h * 8192 + lds_wbase];
        gld_lds16(g, l);
        gld_lds16(g + (size_t)64 * K, l + 4096);
    };

    // prologue: tile0 complete (B0,B1,A0,A1) + tile1 B0,B1,A0 -> 14 loads in flight;
    // retire tile0's 8, keep tile1's 6 in flight.
    stageB(0, 0); stageB(0, 1); stageA(0, 0); stageA(0, 1);
    stageB(1, 0); stageB(1, 1); stageA(1, 0);
    asm volatile("s_waitcnt vmcnt(6)" ::: "memory");
    __builtin_amdgcn_s_barrier();

    f32x4 acc[8][4] = {};
    short8 bf[4][2];

    const int NT = K / BK;
    for (int u = 0; u < NT; ++u) {
        const unsigned short* as = &As[u & 1][0];
        const unsigned short* bs = &Bs[u & 1][0];
        const bool s1 = (u + 1 < NT);
        const bool s2 = (u + 2 < NT);

#pragma unroll
        for (int q = 0; q < 4; ++q) {
            // ---- stage one half-tile of a future K-tile ----
            if (q == 0)      { if (s1) stageA(u + 1, 1); }
            else if (q == 1) { if (s2) stageB(u + 2, 0); }
            else if (q == 2) { if (s2) stageB(u + 2, 1); }
            else             { if (s2) stageA(u + 2, 0); }

            // ---- ds_read register fragments (swizzled slots; measured conflict-free) ----
            if (q == 0) {
#pragma unroll
                for (int j = 0; j < 4; ++j) {
                    int brow = wn * 64 + j * 16 + lm;
#pragma unroll
                    for (int ks = 0; ks < 2; ++ks)
                        bf[j][ks] = *(const short8*)&bs[brow * 64 + (((ks * 4 + quad) ^ (brow & 7)) * 8)];
                }
            }
            short8 af[2][2];
            const int arow0 = q * 64 + wm * 32 + lm;
#pragma unroll
            for (int i = 0; i < 2; ++i) {
                int arow = arow0 + i * 16;
#pragma unroll
                for (int ks = 0; ks < 2; ++ks)
                    af[i][ks] = *(const short8*)&as[arow * 64 + (((ks * 4 + quad) ^ (arow & 7)) * 8)];
            }

            __builtin_amdgcn_s_barrier();
            asm volatile("s_waitcnt lgkmcnt(0)" ::: "memory");
            __builtin_amdgcn_s_setprio(1);
#pragma unroll
            for (int ks = 0; ks < 2; ++ks)
#pragma unroll
                for (int i = 0; i < 2; ++i)
#pragma unroll
                    for (int j = 0; j < 4; ++j)
                        acc[q * 2 + i][j] = __builtin_amdgcn_mfma_f32_16x16x32_bf16(
                            af[i][ks], bf[j][ks], acc[q * 2 + i][j], 0, 0, 0);
            __builtin_amdgcn_s_setprio(0);

            if (q == 3) {
                // once per K-tile; steady state keeps 3 half-tiles (6 loads) in flight
                if (s2)      { asm volatile("s_waitcnt vmcnt(6)" ::: "memory"); }
                else if (s1) { asm volatile("s_waitcnt vmcnt(0)" ::: "memory"); }
            }
            __builtin_amdgcn_s_barrier();
        }
    }

    // epilogue: C/D layout col=lane&15, row=quad*4+reg; + bias
#pragma unroll
    for (int j = 0; j < 4; ++j) {
        const int col = tile_n + wn * 64 + j * 16 + lm;
        const float bv = bias[col];
#pragma unroll
        for (int m = 0; m < 8; ++m) {
            const int row0 = tile_m + (m >> 1) * 64 + wm * 32 + (m & 1) * 16 + quad * 4;
#pragma unroll
            for (int r = 0; r < 4; ++r)
                C[(size_t)(row0 + r) * N + col] = acc[m][j][r] + bv;
        }
    }
}

// ---------------- fallback: fp32 tiled GEMM with on-the-fly binarize (correctness net) ----------------
__global__ void gemm_fallback_kernel(const float* __restrict__ A, const float* __restrict__ W,
                                     const float* __restrict__ bias, const float* __restrict__ bounds,
                                     float* __restrict__ C, int M, int N, int K) {
    __shared__ float as[16][16];
    __shared__ float wsm[16][17];
    int tx = threadIdx.x, ty = threadIdx.y;
    int row = blockIdx.y * 16 + ty;
    int col = blockIdx.x * 16 + tx;
    float lo = bounds[0], hi = bounds[1];
    float acc = 0.f;
    for (int k0 = 0; k0 < K; k0 += 16) {
        as[ty][tx] = A[(size_t)row * K + k0 + tx];
        float wv = W[(size_t)(blockIdx.x * 16 + ty) * K + k0 + tx];
        bool outlier = (wv < lo) || (wv > hi);
        wsm[ty][tx] = outlier ? wv : (wv > 0.f ? 1.f : (wv < 0.f ? -1.f : 0.f));
        __syncthreads();
#pragma unroll
        for (int k = 0; k < 16; k++) acc += as[ty][k] * wsm[tx][k];
        __syncthreads();
    }
    C[(size_t)row * N + col] = acc + bias[col];
}

extern "C" void kernel_launch(void* const* d_in, const int* in_sizes, int n_in,
                              void* d_out, int out_size, void* d_ws, size_t ws_size,
                              hipStream_t stream) {
    const float* x    = (const float*)d_in[0];
    const float* w    = (const float*)d_in[1];
    const float* bias = (const float*)d_in[2];
    float* out = (float*)d_out;

    const int  N  = in_sizes[2];                 // 4096
    const long wn = (long)in_sizes[1];           // 16777216
    const int  K  = (int)(wn / N);               // 4096
    const long xn = (long)in_sizes[0];           // 67108864
    const int  M  = (int)(xn / K);               // 16384

    char* ws = (char*)d_ws;
    float*  bounds   = (float*)ws;                       // 8 B
    double* partials = (double*)(ws + 64);               // 1024 * 16 B = 16 KB
    const size_t wb_off = 16512;                         // 64+16384 rounded; 128B aligned
    unsigned short* wb = (unsigned short*)(ws + wb_off); // 32 MB
    const size_t xb_off = wb_off + (size_t)wn * 2;
    unsigned short* xb = (unsigned short*)(ws + xb_off); // 128 MB
    const size_t need_full = xb_off + (size_t)xn * 2;

    // stats (always)
    stats_partial_kernel<<<1024, 256, 0, stream>>>(w, (int)(wn / 4), partials);
    stats_final_kernel<<<1, 256, 0, stream>>>(partials, 1024, wn, bounds);

    const bool ok256 = (M % 256 == 0) && (N % 256 == 0) && (K % 64 == 0) && (K / 64 >= 3)
                       && (wn % 8 == 0) && (xn % 8 == 0);

    if (ws_size >= need_full && ok256) {
        long wn8 = wn / 8, xn8 = xn / 8;
        int bb = (int)((wn8 + 255) / 256); if (bb > 2048) bb = 2048;
        int cb = (int)((xn8 + 255) / 256); if (cb > 2048) cb = 2048;
        binarize_w_kernel<<<bb, 256, 0, stream>>>(w, bounds, wb, wn8);
        convert_x_kernel<<<cb, 256, 0, stream>>>(x, xb, xn8);
        dim3 grid((M / BM) * (N / BN));
        gemm_8phase_kernel<<<grid, 512, 0, stream>>>(xb, wb, bias, out, M, N, K);
    } else {
        dim3 grid(N / 16, M / 16), blk(16, 16);
        gemm_fallback_kernel<<<grid, blk, 0, stream>>>(x, w, bias, bounds, out, M, N, K);
    }
}

// Round 2
// 1048.753 us; speedup vs baseline: 1.1501x; 1.0324x over previous
//
#include <hip/hip_runtime.h>
#include <stdint.h>
#include <math.h>

typedef __attribute__((ext_vector_type(8))) short short8;
typedef __attribute__((ext_vector_type(4))) float f32x4;

typedef const __attribute__((address_space(1))) void* gas_ptr;
typedef __attribute__((address_space(3))) void* las_ptr;

__device__ __forceinline__ void gld_lds16(const void* g, void* l) {
    // async global->LDS, 16B per lane, LDS dest = wave-uniform base + lane*16
    __builtin_amdgcn_global_load_lds((gas_ptr)g, (las_ptr)l, 16, 0, 0);
}

__device__ __forceinline__ unsigned short f32_to_bf16_rne(float f) {
    unsigned u = __builtin_bit_cast(unsigned, f);
    u += 0x7FFFu + ((u >> 16) & 1u);
    return (unsigned short)(u >> 16);
}

// ---------------- stats: pass 1 (per-block partial sum/sumsq in double) ----------------
__global__ void stats_partial_kernel(const float* __restrict__ w, int n4, double* __restrict__ partials) {
    __shared__ double ssum[256];
    __shared__ double ssq[256];
    int t = threadIdx.x;
    long i = (long)blockIdx.x * blockDim.x + t;
    long stride = (long)gridDim.x * blockDim.x;
    double s = 0.0, q = 0.0;
    for (; i < n4; i += stride) {
        float4 v = ((const float4*)w)[i];
        s += (double)v.x + (double)v.y + (double)v.z + (double)v.w;
        q += (double)v.x * v.x + (double)v.y * v.y + (double)v.z * v.z + (double)v.w * v.w;
    }
    ssum[t] = s; ssq[t] = q;
    __syncthreads();
    for (int off = 128; off > 0; off >>= 1) {
        if (t < off) { ssum[t] += ssum[t + off]; ssq[t] += ssq[t + off]; }
        __syncthreads();
    }
    if (t == 0) {
        partials[2 * blockIdx.x]     = ssum[0];
        partials[2 * blockIdx.x + 1] = ssq[0];
    }
}

// ---------------- stats: pass 2 (finalize -> lower/upper bounds as float) ----------------
__global__ void stats_final_kernel(const double* __restrict__ partials, int nblocks, long n,
                                   float* __restrict__ bounds) {
    __shared__ double ssum[256];
    __shared__ double ssq[256];
    int t = threadIdx.x;
    double s = 0.0, q = 0.0;
    for (int i = t; i < nblocks; i += 256) {
        s += partials[2 * i];
        q += partials[2 * i + 1];
    }
    ssum[t] = s; ssq[t] = q;
    __syncthreads();
    for (int off = 128; off > 0; off >>= 1) {
        if (t < off) { ssum[t] += ssum[t + off]; ssq[t] += ssq[t + off]; }
        __syncthreads();
    }
    if (t == 0) {
        double sum = ssum[0], sumsq = ssq[0];
        double mean = sum / (double)n;
        double var = (sumsq - sum * sum / (double)n) / (double)(n - 1); // ddof=1
        double sd = sqrt(var);
        bounds[0] = (float)(mean - sd);
        bounds[1] = (float)(mean + sd);
    }
}

// ---------------- binarize weight -> bf16 bits (grid-stride, 8 elems/thread/iter) ----------------
__global__ void binarize_w_kernel(const float* __restrict__ w, const float* __restrict__ bounds,
                                  unsigned short* __restrict__ wb, long n8) {
    float lo = bounds[0], hi = bounds[1];
    long i = (long)blockIdx.x * blockDim.x + threadIdx.x;
    long stride = (long)gridDim.x * blockDim.x;
    for (; i < n8; i += stride) {
        float4 v0 = ((const float4*)w)[2 * i];
        float4 v1 = ((const float4*)w)[2 * i + 1];
        float r[8] = {v0.x, v0.y, v0.z, v0.w, v1.x, v1.y, v1.z, v1.w};
        short8 o;
#pragma unroll
        for (int j = 0; j < 8; j++) {
            float f = r[j];
            bool outlier = (f < lo) || (f > hi);
            float b = outlier ? f : (f > 0.f ? 1.f : (f < 0.f ? -1.f : 0.f));
            o[j] = (short)f32_to_bf16_rne(b);
        }
        ((short8*)wb)[i] = o;
    }
}

// ---------------- convert x -> bf16 bits (grid-stride, 8 elems/thread/iter) ----------------
__global__ void convert_x_kernel(const float* __restrict__ x, unsigned short* __restrict__ xb, long n8) {
    long i = (long)blockIdx.x * blockDim.x + threadIdx.x;
    long stride = (long)gridDim.x * blockDim.x;
    for (; i < n8; i += stride) {
        float4 v0 = ((const float4*)x)[2 * i];
        float4 v1 = ((const float4*)x)[2 * i + 1];
        short8 o;
        o[0] = (short)f32_to_bf16_rne(v0.x);
        o[1] = (short)f32_to_bf16_rne(v0.y);
        o[2] = (short)f32_to_bf16_rne(v0.z);
        o[3] = (short)f32_to_bf16_rne(v0.w);
        o[4] = (short)f32_to_bf16_rne(v1.x);
        o[5] = (short)f32_to_bf16_rne(v1.y);
        o[6] = (short)f32_to_bf16_rne(v1.z);
        o[7] = (short)f32_to_bf16_rne(v1.w);
        ((short8*)xb)[i] = o;
    }
}

// ---------------- bf16 MFMA GEMM, 256x256, 4-phase pipelined (1 barrier/phase) ----------------
// C[M,N] = A[M,K] * B[N,K]^T + bias. 512 threads = 8 waves (2M x 4N), each wave 128x64.
// BK=64; LDS = 2 x (A 32KB + B 32KB) = 128KB double buffer.
//
// Schedule per K-tile u (4 phases, ONE barrier each, counted vmcnt once per tile):
//   p0: stage (u+1).A1; ds_read B(8) + A_p0(4) + A_p1(4); MFMA p0 (lgkm waits only B+A_p0,
//       A_p1 reads fly under the MFMAs); barrier
//   p1: stage (u+2).B0; ds_read A_p2(4); MFMA p1; barrier
//   p2: stage (u+2).B1; ds_read A_p3(4); MFMA p2; barrier
//   p3: stage (u+2).A0; MFMA p3; vmcnt(6); barrier
// WAR safety: a region's readers retire at their lgkm-wait BEFORE the phase-end barrier;
// its re-stage is issued only AFTER that barrier. RAW safety: tile u's data fully retired
// by tile u-1's vmcnt(6) + barrier. Steady state keeps 3 half-tiles (6 loads) in flight.
#define BM 256
#define BN 256
#define BK 64

__global__ __launch_bounds__(512, 2) void gemm_8phase_kernel(
    const unsigned short* __restrict__ A,   // [M,K] bf16 bits
    const unsigned short* __restrict__ B,   // [N,K] bf16 bits
    const float* __restrict__ bias,         // [N]
    float* __restrict__ C,                  // [M,N] fp32
    int M, int N, int K)
{
    __shared__ __align__(16) unsigned short As[2][BM * BK]; // 2 x 32KB
    __shared__ __align__(16) unsigned short Bs[2][BN * BK]; // 2 x 32KB

    const int t = threadIdx.x;
    const int wave = t >> 6;
    const int lane = t & 63;
    const int wm = wave >> 2;      // 0..1 -> 32-row group within each 64-row phase block
    const int wn = wave & 3;       // 0..3 -> 64-col block
    const int lm = lane & 15;
    const int quad = lane >> 4;

    // XCD-aware bijective swizzle (gridDim.x % 8 == 0 here: 64*16 = 1024)
    const int nwg = gridDim.x;
    int id = blockIdx.x;
    if ((nwg & 7) == 0) id = (id & 7) * (nwg >> 3) + (id >> 3);
    const int nbn = N / BN;
    const int tile_m = (id / nbn) * BM;
    const int tile_n = (id % nbn) * BN;

    // staging geometry: one issue = 512 threads x 16B = 64 rows x 64 cols.
    // thread t covers chunk t: row = t>>3, lds slot = t&7, global chunk = slot ^ (row&7)
    // (pre-swizzled global source; LDS dest stays linear for global_load_lds)
    const int srow = t >> 3;
    const int scol = ((t & 7) ^ (srow & 7)) * 8;
    const int lds_wbase = wave * 512;

    const unsigned short* Abase = A + (size_t)tile_m * K;
    const unsigned short* Bbase = B + (size_t)tile_n * K;

    auto stageA = [&](int u2, int h) {
        const unsigned short* g = Abase + (size_t)(h * 128 + srow) * K + u2 * BK + scol;
        unsigned short* l = &As[u2 & 1][h * 8192 + lds_wbase];
        gld_lds16(g, l);
        gld_lds16(g + (size_t)64 * K, l + 4096);
    };
    auto stageB = [&](int u2, int h) {
        const unsigned short* g = Bbase + (size_t)(h * 128 + srow) * K + u2 * BK + scol;
        unsigned short* l = &Bs[u2 & 1][h * 8192 + lds_wbase];
        gld_lds16(g, l);
        gld_lds16(g + (size_t)64 * K, l + 4096);
    };

    // prologue: tile0 complete (B0,B1,A0,A1) + tile1 B0,B1,A0 -> 14 loads in flight;
    // retire tile0's 8, keep tile1's 6 in flight.
    stageB(0, 0); stageB(0, 1); stageA(0, 0); stageA(0, 1);
    stageB(1, 0); stageB(1, 1); stageA(1, 0);
    asm volatile("s_waitcnt vmcnt(6)" ::: "memory");
    __builtin_amdgcn_s_barrier();

    f32x4 acc[8][4] = {};

    const int NT = K / BK;
    for (int u = 0; u < NT; ++u) {
        const unsigned short* as = &As[u & 1][0];
        const unsigned short* bs = &Bs[u & 1][0];
        const bool s1 = (u + 1 < NT);
        const bool s2 = (u + 2 < NT);

        short8 bf[4][2];

        auto lda = [&](short8 (&af)[2][2], int q) {
#pragma unroll
            for (int i = 0; i < 2; ++i) {
                int arow = q * 64 + wm * 32 + i * 16 + lm;
#pragma unroll
                for (int ks = 0; ks < 2; ++ks)
                    af[i][ks] = *(const short8*)&as[arow * 64 + (((ks * 4 + quad) ^ (arow & 7)) * 8)];
            }
        };
        auto mm = [&](short8 (&af)[2][2], int q) {
            __builtin_amdgcn_s_setprio(1);
#pragma unroll
            for (int ks = 0; ks < 2; ++ks)
#pragma unroll
                for (int i = 0; i < 2; ++i)
#pragma unroll
                    for (int j = 0; j < 4; ++j)
                        acc[q * 2 + i][j] = __builtin_amdgcn_mfma_f32_16x16x32_bf16(
                            af[i][ks], bf[j][ks], acc[q * 2 + i][j], 0, 0, 0);
            __builtin_amdgcn_s_setprio(0);
        };

        // ---------- phase 0 ----------
        if (s1) stageA(u + 1, 1);
#pragma unroll
        for (int j = 0; j < 4; ++j) {
            int brow = wn * 64 + j * 16 + lm;
#pragma unroll
            for (int ks = 0; ks < 2; ++ks)
                bf[j][ks] = *(const short8*)&bs[brow * 64 + (((ks * 4 + quad) ^ (brow & 7)) * 8)];
        }
        short8 af0[2][2], af1[2][2];
        lda(af0, 0);
        lda(af1, 1);           // prefetch: flies under MFMA p0
        mm(af0, 0);
        __builtin_amdgcn_s_barrier();

        // ---------- phase 1 ----------
        if (s2) stageB(u + 2, 0);
        short8 af2[2][2];
        lda(af2, 2);           // prefetch: flies under MFMA p1
        mm(af1, 1);
        __builtin_amdgcn_s_barrier();

        // ---------- phase 2 ----------
        if (s2) stageB(u + 2, 1);
        short8 af3[2][2];
        lda(af3, 3);           // prefetch: flies under MFMA p2
        mm(af2, 2);
        __builtin_amdgcn_s_barrier();

        // ---------- phase 3 ----------
        if (s2) stageA(u + 2, 0);
        mm(af3, 3);
        if (s2)      { asm volatile("s_waitcnt vmcnt(6)" ::: "memory"); }
        else if (s1) { asm volatile("s_waitcnt vmcnt(0)" ::: "memory"); }
        __builtin_amdgcn_s_barrier();
    }

    // epilogue: C/D layout col=lane&15, row=quad*4+reg; + bias
#pragma unroll
    for (int j = 0; j < 4; ++j) {
        const int col = tile_n + wn * 64 + j * 16 + lm;
        const float bv = bias[col];
#pragma unroll
        for (int m = 0; m < 8; ++m) {
            const int row0 = tile_m + (m >> 1) * 64 + wm * 32 + (m & 1) * 16 + quad * 4;
#pragma unroll
            for (int r = 0; r < 4; ++r)
                C[(size_t)(row0 + r) * N + col] = acc[m][j][r] + bv;
        }
    }
}

// ---------------- fallback: fp32 tiled GEMM with on-the-fly binarize (correctness net) ----------------
__global__ void gemm_fallback_kernel(const float* __restrict__ A, const float* __restrict__ W,
                                     const float* __restrict__ bias, const float* __restrict__ bounds,
                                     float* __restrict__ C, int M, int N, int K) {
    __shared__ float as[16][16];
    __shared__ float wsm[16][17];
    int tx = threadIdx.x, ty = threadIdx.y;
    int row = blockIdx.y * 16 + ty;
    int col = blockIdx.x * 16 + tx;
    float lo = bounds[0], hi = bounds[1];
    float acc = 0.f;
    for (int k0 = 0; k0 < K; k0 += 16) {
        as[ty][tx] = A[(size_t)row * K + k0 + tx];
        float wv = W[(size_t)(blockIdx.x * 16 + ty) * K + k0 + tx];
        bool outlier = (wv < lo) || (wv > hi);
        wsm[ty][tx] = outlier ? wv : (wv > 0.f ? 1.f : (wv < 0.f ? -1.f : 0.f));
        __syncthreads();
#pragma unroll
        for (int k = 0; k < 16; k++) acc += as[ty][k] * wsm[tx][k];
        __syncthreads();
    }
    C[(size_t)row * N + col] = acc + bias[col];
}

extern "C" void kernel_launch(void* const* d_in, const int* in_sizes, int n_in,
                              void* d_out, int out_size, void* d_ws, size_t ws_size,
                              hipStream_t stream) {
    const float* x    = (const float*)d_in[0];
    const float* w    = (const float*)d_in[1];
    const float* bias = (const float*)d_in[2];
    float* out = (float*)d_out;

    const int  N  = in_sizes[2];                 // 4096
    const long wn = (long)in_sizes[1];           // 16777216
    const int  K  = (int)(wn / N);               // 4096
    const long xn = (long)in_sizes[0];           // 67108864
    const int  M  = (int)(xn / K);               // 16384

    char* ws = (char*)d_ws;
    float*  bounds   = (float*)ws;                       // 8 B
    double* partials = (double*)(ws + 64);               // 1024 * 16 B = 16 KB
    const size_t wb_off = 16512;                         // 64+16384 rounded; 128B aligned
    unsigned short* wb = (unsigned short*)(ws + wb_off); // 32 MB
    const size_t xb_off = wb_off + (size_t)wn * 2;
    unsigned short* xb = (unsigned short*)(ws + xb_off); // 128 MB
    const size_t need_full = xb_off + (size_t)xn * 2;

    // stats (always)
    stats_partial_kernel<<<1024, 256, 0, stream>>>(w, (int)(wn / 4), partials);
    stats_final_kernel<<<1, 256, 0, stream>>>(partials, 1024, wn, bounds);

    const bool ok256 = (M % 256 == 0) && (N % 256 == 0) && (K % 64 == 0) && (K / 64 >= 3)
                       && (wn % 8 == 0) && (xn % 8 == 0);

    if (ws_size >= need_full && ok256) {
        long wn8 = wn / 8, xn8 = xn / 8;
        int bb = (int)((wn8 + 255) / 256); if (bb > 2048) bb = 2048;
        int cb = (int)((xn8 + 255) / 256); if (cb > 2048) cb = 2048;
        binarize_w_kernel<<<bb, 256, 0, stream>>>(w, bounds, wb, wn8);
        convert_x_kernel<<<cb, 256, 0, stream>>>(x, xb, xn8);
        dim3 grid((M / BM) * (N / BN));
        gemm_8phase_kernel<<<grid, 512, 0, stream>>>(xb, wb, bias, out, M, N, K);
    } else {
        dim3 grid(N / 16, M / 16), blk(16, 16);
        gemm_fallback_kernel<<<grid, blk, 0, stream>>>(x, w, bias, bounds, out, M, N, K);
    }
}